// Round 5
// baseline (148.844 us; speedup 1.0000x reference)
//
#include <hip/hip_runtime.h>

#define W0 0.4f
#define W1 1.6f

#define TILE 2048            // elements per tile
#define TPB  16384           // elements per block
#define NTILES (TPB / TILE)  // 8

typedef __attribute__((address_space(3))) void lds_t;
typedef const __attribute__((address_space(1))) void gbl_t;

// 1024 blocks x 256 threads. Each block streams 16384 elems through LDS via
// global_load_lds DMA (no VGPRs in flight), double-buffered 2048-elem tiles.
// Raw s_barrier + vmcnt(4) keeps next-tile DMAs in flight across the barrier.
// LDS: 2*(8KB in + 8KB tg) = 32KB -> 4 blocks/CU.

__global__ __launch_bounds__(256, 4) void bce_reduce_kernel(
    const float* __restrict__ input,
    const int* __restrict__ target,
    float* __restrict__ psum,
    unsigned int* __restrict__ pcnt)
{
    __shared__ float s_in[2][TILE];
    __shared__ int   s_tg[2][TILE];

    const int tid  = threadIdx.x;
    const int wave = tid >> 6;
    const int lane = tid & 63;
    const long base = (long)blockIdx.x * TPB;

    // Stage tile t into buffer b. Each wave DMAs its 512-elem (2KB) quarter of
    // input and target: 2+2 dwordx4-LDS instructions, 1KB each.
    // gptr is per-lane (base + lane*16B); lds ptr is the wave-uniform base
    // (HW adds lane*16 itself).
#define STAGE(b, t)                                                            \
    {                                                                          \
        const long e0 = base + (long)(t) * TILE + wave * 512;                  \
        const float* gi = input + e0 + lane * 4;                               \
        const int*   gt = target + e0 + lane * 4;                              \
        __builtin_amdgcn_global_load_lds((gbl_t*)(gi),                         \
            (lds_t*)&s_in[b][wave * 512], 16, 0, 0);                           \
        __builtin_amdgcn_global_load_lds((gbl_t*)(gi + 256),                   \
            (lds_t*)&s_in[b][wave * 512 + 256], 16, 0, 0);                     \
        __builtin_amdgcn_global_load_lds((gbl_t*)(gt),                         \
            (lds_t*)&s_tg[b][wave * 512], 16, 0, 0);                           \
        __builtin_amdgcn_global_load_lds((gbl_t*)(gt + 256),                   \
            (lds_t*)&s_tg[b][wave * 512 + 256], 16, 0, 0);                     \
    }

    float sum = 0.0f;
    unsigned int correct = 0;

#define ELEM(P, T)                                                             \
    {                                                                          \
        bool pos = ((T) != 0);                                                 \
        float x = pos ? (P) : (1.0f - (P));                                    \
        float w = pos ? W1 : W0;                                               \
        sum = __builtin_fmaf(__logf(x), w, sum);                               \
        correct += (((P) > 0.5f) == pos) ? 1u : 0u;                            \
    }

    STAGE(0, 0);

    #pragma unroll 1
    for (int t = 0; t < NTILES; ++t) {
        if (t + 1 < NTILES) {
            STAGE((t + 1) & 1, t + 1);
            // tile t's 4 DMAs are the oldest; keep tile t+1's 4 in flight.
            asm volatile("s_waitcnt vmcnt(4)\n\ts_barrier" ::: "memory");
        } else {
            asm volatile("s_waitcnt vmcnt(0)\n\ts_barrier" ::: "memory");
        }
        const int b = t & 1;
        float4 p0 = ((const float4*)s_in[b])[tid];
        float4 p1 = ((const float4*)s_in[b])[tid + 256];
        int4   t0 = ((const int4*)s_tg[b])[tid];
        int4   t1 = ((const int4*)s_tg[b])[tid + 256];

        ELEM(p0.x, t0.x) ELEM(p0.y, t0.y) ELEM(p0.z, t0.z) ELEM(p0.w, t0.w)
        ELEM(p1.x, t1.x) ELEM(p1.y, t1.y) ELEM(p1.z, t1.z) ELEM(p1.w, t1.w)

        // All waves done reading buf b before anyone DMAs over it next iter.
        asm volatile("s_barrier" ::: "memory");
    }
#undef ELEM
#undef STAGE

    #pragma unroll
    for (int off = 32; off > 0; off >>= 1) {
        sum     += __shfl_down(sum, off, 64);
        correct += __shfl_down(correct, off, 64);
    }

    __shared__ float s_sum[4];
    __shared__ unsigned int s_cnt[4];
    if (lane == 0) { s_sum[wave] = sum; s_cnt[wave] = correct; }
    __syncthreads();
    if (tid == 0) {
        float bs = s_sum[0] + s_sum[1] + s_sum[2] + s_sum[3];
        unsigned int bc = s_cnt[0] + s_cnt[1] + s_cnt[2] + s_cnt[3];
        psum[blockIdx.x] = bs;
        pcnt[blockIdx.x] = bc;
    }
}

__global__ __launch_bounds__(1024) void bce_finalize_kernel(
    const float* __restrict__ psum,
    const unsigned int* __restrict__ pcnt,
    float* __restrict__ out, int nblocks, int n)
{
    const int tid = threadIdx.x;
    double s = 0.0;
    unsigned long long c = 0;
    for (int k = tid; k < nblocks; k += 1024) {
        s += (double)psum[k];
        c += (unsigned long long)pcnt[k];
    }
    #pragma unroll
    for (int off = 32; off > 0; off >>= 1) {
        s += __shfl_down(s, off, 64);
        c += __shfl_down(c, off, 64);
    }
    __shared__ double sh_s[16];
    __shared__ unsigned long long sh_c[16];
    const int lane = tid & 63;
    const int wave = tid >> 6;
    if (lane == 0) { sh_s[wave] = s; sh_c[wave] = c; }
    __syncthreads();
    if (tid == 0) {
        double ts = 0.0;
        unsigned long long tc = 0;
        for (int w = 0; w < 16; ++w) { ts += sh_s[w]; tc += sh_c[w]; }
        double inv_n = 1.0 / (double)n;
        out[0] = (float)(-ts * inv_n);
        out[1] = (float)((double)tc * inv_n);
    }
}

extern "C" void kernel_launch(void* const* d_in, const int* in_sizes, int n_in,
                              void* d_out, int out_size, void* d_ws, size_t ws_size,
                              hipStream_t stream) {
    const float* input  = (const float*)d_in[0];
    const int*   target = (const int*)d_in[1];
    float* out = (float*)d_out;
    int n = in_sizes[0];
    int nblocks = n / TPB;  // 1024

    float* psum = (float*)d_ws;
    unsigned int* pcnt = (unsigned int*)((char*)d_ws + (size_t)nblocks * sizeof(float));

    bce_reduce_kernel<<<nblocks, 256, 0, stream>>>(input, target, psum, pcnt);
    bce_finalize_kernel<<<1, 1024, 0, stream>>>(psum, pcnt, out, nblocks, n);
}